// Round 6
// baseline (41688.052 us; speedup 1.0000x reference)
//
#include <hip/hip_runtime.h>
#include <hip/hip_bf16.h>

#define T_ 512
#define B_ 128
#define D_ 256
#define H_ 256
#define EPS 1e-5f

typedef __attribute__((ext_vector_type(8))) short short8;
typedef __attribute__((ext_vector_type(4))) short short4v;
typedef __attribute__((ext_vector_type(4))) float f32x4;

// bf16 weight arena layout in d_ws (element offsets, bf16/short):
#define WT1A_OFF 0         // [768][512]  n: 0-255 Wr, 256-511 Wz, 512-767 Wl ; k: 0-255 x, 256-511 h
#define WT1B_OFF 393216    // [512][256]  n: 0-255 Cx, 256-511 Wlt            ; A = x
#define WT1C_OFF 524288    // [256][256]  Ch_w                                 ; A = h
#define WTT_OFF  589824    // [4][768][256] per layer: n 0-255 tWr, 256-511 tWz, 512-767 tWc
#define WTT_PER  196608
#define WT_TOTAL 1376256

__device__ __forceinline__ short f2bf(float f) {
  unsigned u = __builtin_bit_cast(unsigned, f);
  u = (u + 0x7FFFu + ((u >> 16) & 1u)) >> 16;   // RNE
  return (short)u;
}

__device__ __forceinline__ f32x4 zero4() { f32x4 z = {0.f, 0.f, 0.f, 0.f}; return z; }

__device__ __forceinline__ f32x4 mfma16(short8 a, short8 b, f32x4 c) {
  return __builtin_amdgcn_mfma_f32_16x16x32_bf16(a, b, c, 0, 0, 0);
}

__device__ __forceinline__ void red2(float& a, float& b) {
  #pragma unroll
  for (int off = 32; off; off >>= 1) {
    a += __shfl_xor(a, off);
    b += __shfl_xor(b, off);
  }
}

// LayerNorm over 256 values spread across the wave (4/lane) -> sigmoid
__device__ __forceinline__ f32x4 ln_sig(f32x4 v, f32x4 g, f32x4 bb) {
  float s1 = v[0] + v[1] + v[2] + v[3];
  float s2 = v[0]*v[0] + v[1]*v[1] + v[2]*v[2] + v[3]*v[3];
  red2(s1, s2);
  float m = s1 * (1.f / 256.f);
  float var = s2 * (1.f / 256.f) - m * m;
  float rs = rsqrtf((var > 0.f ? var : 0.f) + EPS);
  f32x4 o;
  #pragma unroll
  for (int i = 0; i < 4; ++i) {
    float t = (v[i] - m) * rs * g[i] + bb[i];
    o[i] = 1.f / (1.f + __expf(-t));
  }
  return o;
}

// ---------------- weight prep: f32 -> bf16, transposed to [n][k] ----------------
__global__ void prep_weights(const float* __restrict__ Wr, const float* __restrict__ Wz,
                             const float* __restrict__ Wl, const float* __restrict__ Wlt,
                             const float* __restrict__ Cx, const float* __restrict__ Chw,
                             const float* __restrict__ tWr, const float* __restrict__ tWz,
                             const float* __restrict__ tWc, short* __restrict__ wt) {
  int idx = blockIdx.x * 256 + threadIdx.x;
  if (idx >= WT_TOTAL) return;
  float v;
  if (idx < WT1B_OFF) {                       // WT1a [768][512]
    int n = idx >> 9, k = idx & 511;
    const float* W = (n < 256) ? Wr : (n < 512 ? Wz : Wl);
    v = W[k * 256 + (n & 255)];
  } else if (idx < WT1C_OFF) {                // WT1b [512][256]
    int r = idx - WT1B_OFF;
    int n = r >> 8, k = r & 255;
    v = (n < 256) ? Cx[k * 256 + n] : Wlt[k * 256 + (n - 256)];
  } else if (idx < WTT_OFF) {                 // WT1c [256][256]
    int r = idx - WT1C_OFF;
    int n = r >> 8, k = r & 255;
    v = Chw[k * 256 + n];
  } else {                                    // WTt [4][768][256]
    int r = idx - WTT_OFF;
    int i = r / WTT_PER;
    int rr = r - i * WTT_PER;
    int n = rr >> 8, k = rr & 255;
    const float* W = (n < 256) ? tWr : (n < 512 ? tWz : tWc);
    v = W[(i * 256 + k) * 256 + (n & 255)];
  }
  wt[idx] = f2bf(v);
}

// --------- zero-sync persistent kernel: 8 WGs (1/XCD) x 16 batch rows ----------
// 8 waves/WG. Weight stream pipelined 2-deep in registers (B0/B1 ping-pong),
// chain threaded across ALL phases so loads are always in flight.
__global__ __launch_bounds__(512)
void rnn8(const float* __restrict__ x, const int* __restrict__ lengths,
          const float* __restrict__ gr, const float* __restrict__ br,
          const float* __restrict__ gz, const float* __restrict__ bz,
          const float* __restrict__ gl, const float* __restrict__ bl,
          const float* __restrict__ Chb,
          const float* __restrict__ tgr, const float* __restrict__ tbr,
          const float* __restrict__ tgz, const float* __restrict__ tbz,
          const float* __restrict__ tbc,
          const short* __restrict__ W, float* __restrict__ out) {

  __shared__ __align__(16) char smem[132096];
  char*  HBF = smem;                       // [16][256] bf16, XOR-swizzled  (8 KB)
  char*  XBF = smem + 8192;                // [16][256] bf16, XOR-swizzled  (8 KB)
  float* HF  = (float*)(smem + 16384);     // [16][256] f32 h master        (16 KB)
  float* G   = (float*)(smem + 32768);     // [16][776] f32 gates/trans     (48.5 KB)
  float* G2  = (float*)(smem + 82432);     // [16][776] f32 xcx|xwl|hch     (48.5 KB)

  const int tid = threadIdx.x;
  const int w   = tid >> 6, l = tid & 63;  // 8 waves
  const int la  = l & 15, lh = l >> 4;
  const int amask = (la & 7) << 4;
  const int rb0 = blockIdx.x * 16;
  const int c0e = 4 * l;

  for (int i = tid; i < 1024; i += 512) ((short4v*)HBF)[i] = (short4v){0, 0, 0, 0};
  for (int i = tid; i < 1024; i += 512) ((f32x4*)HF)[i] = zero4();

  int maxlen = 0;
  for (int i = 0; i < 16; ++i) {
    int v = lengths[rb0 + i];
    maxlen = maxlen > v ? maxlen : v;
  }
  const int lenA = lengths[rb0 + 2 * w];
  const int lenB = lengths[rb0 + 2 * w + 1];

  // per-wave weight base pointers ([n][k] arena; n = tile*16+la, frag k-offset lh*8)
  const short* bg = W + WT1A_OFF + (size_t)((w * 6) * 16 + la) * 512 + lh * 8;  // 6 gate tiles, +s*8192
  const short* bx = W + WT1B_OFF + (size_t)((w * 4) * 16 + la) * 256 + lh * 8;  // 4 xcw tiles, +q*4096
  const short* bh = W + WT1C_OFF + (size_t)((w * 2) * 16 + la) * 256 + lh * 8;  // 2 hch tiles, +q*4096
  const short* bt = W + WTT_OFF + (size_t)((w * 6) * 16 + la) * 256 + lh * 8;   // 6 tiles/layer, +li*WTT_PER+s*4096

  // ---- pipelined streaming helpers (arrays only with static indices) ----
  auto ld8 = [&](short8 (&dst)[8], const short* bp) {
    #pragma unroll
    for (int kf = 0; kf < 8; ++kf) dst[kf] = *(const short8*)(bp + kf * 32);
  };
  auto mm8x = [&](short8 (&b)[8], f32x4& acc) {      // A = XBF
    #pragma unroll
    for (int kf = 0; kf < 8; ++kf) {
      int aoff = la * 512 + (((kf * 64) + lh * 16) ^ amask);
      acc = mfma16(*(const short8*)(XBF + aoff), b[kf], acc);
    }
  };
  auto mm8h = [&](short8 (&b)[8], f32x4& acc) {      // A = HBF
    #pragma unroll
    for (int kf = 0; kf < 8; ++kf) {
      int aoff = la * 512 + (((kf * 64) + lh * 16) ^ amask);
      acc = mfma16(*(const short8*)(HBF + aoff), b[kf], acc);
    }
  };
  auto st4 = [&](float* Gb, int colbase, f32x4 acc) {
    #pragma unroll
    for (int i = 0; i < 4; ++i) Gb[(lh * 4 + i) * 776 + colbase + la] = acc[i];
  };

  short8 B0[8], B1[8];
  ld8(B0, bg);                 // prologue: gates tile0 half0 (x-half)

  __syncthreads();

  for (int t = 0; t < maxlen; ++t) {
    // ---- stage x_t -> XBF (bf16, swizzled) ----
    {
      const float* xt = x + ((size_t)t * B_ + rb0) * D_;
      for (int c = tid; c < 1024; c += 512) {
        int row = c >> 6, j = c & 63;
        f32x4 v = *(const f32x4*)(xt + row * D_ + 4 * j);
        short4v s = { f2bf(v[0]), f2bf(v[1]), f2bf(v[2]), f2bf(v[3]) };
        *(short4v*)(XBF + row * 512 + ((8 * j) ^ ((row & 7) << 4))) = s;
      }
    }
    __syncthreads();

    // ================= G phase: 18 jobs/wave, 2-deep pipeline =================
    // 6 gate tiles (K=512: half0 XBF + half1 HBF share one acc)
    #pragma unroll
    for (int s = 0; s < 6; ++s) {
      const short* bps = bg + (size_t)s * 8192;
      f32x4 acc = zero4();
      ld8(B1, bps + 256);                         // half1 (h-part, k=256..511)
      mm8x(B0, acc);
      if (s < 5) ld8(B0, bps + 8192);             // next tile half0
      else       ld8(B0, bx);                     // first xcw tile
      mm8h(B1, acc);
      st4(G, (w * 6 + s) * 16, acc);
    }
    // 4 xcw tiles (Cx|Wlt, A = XBF)
    #pragma unroll
    for (int q = 0; q < 4; ++q) {
      f32x4 acc = zero4();
      if ((q & 1) == 0) {
        ld8(B1, bx + (size_t)(q + 1) * 4096);
        mm8x(B0, acc);
      } else {
        if (q < 3) ld8(B0, bx + (size_t)(q + 1) * 4096);
        else       ld8(B0, bh);                   // first hch tile
        mm8x(B1, acc);
      }
      st4(G2, (w * 4 + q) * 16, acc);
    }
    // 2 hch tiles (Ch_w, A = HBF)
    {
      f32x4 acc = zero4();
      ld8(B1, bh + 4096);
      mm8h(B0, acc);
      st4(G2, 512 + (w * 2) * 16, acc);
    }
    {
      f32x4 acc = zero4();
      ld8(B0, bt);                                // transition layer0 tile0
      mm8h(B1, acc);
      st4(G2, 512 + (w * 2 + 1) * 16, acc);
    }
    __syncthreads();

    // ---- GRU cell elementwise: wave w -> rows 2w, 2w+1 ----
    {
      f32x4 g4r = *(const f32x4*)(gr + c0e), b4r = *(const f32x4*)(br + c0e);
      f32x4 g4z = *(const f32x4*)(gz + c0e), b4z = *(const f32x4*)(bz + c0e);
      f32x4 g4l = *(const f32x4*)(gl + c0e), b4l = *(const f32x4*)(bl + c0e);
      f32x4 cb4 = *(const f32x4*)(Chb + c0e);
      #pragma unroll
      for (int rr = 0; rr < 2; ++rr) {
        int row = 2 * w + rr;
        f32x4 pr  = *(const f32x4*)&G[row * 776 + c0e];
        f32x4 pz  = *(const f32x4*)&G[row * 776 + 256 + c0e];
        f32x4 pl  = *(const f32x4*)&G[row * 776 + 512 + c0e];
        f32x4 xcx = *(const f32x4*)&G2[row * 776 + c0e];
        f32x4 xwl = *(const f32x4*)&G2[row * 776 + 256 + c0e];
        f32x4 hch = *(const f32x4*)&G2[row * 776 + 512 + c0e];
        f32x4 r4 = ln_sig(pr, g4r, b4r);
        f32x4 z4 = ln_sig(pz, g4z, b4z);
        f32x4 l4 = ln_sig(pl, g4l, b4l);
        f32x4 h = *(const f32x4*)&HF[row * 256 + c0e];
        f32x4 hn;
        #pragma unroll
        for (int q = 0; q < 4; ++q) {
          float n = tanhf(xcx[q] + r4[q] * (hch[q] + cb4[q])) + l4[q] * xwl[q];
          hn[q] = (1.f - z4[q]) * h[q] + z4[q] * n;
        }
        if (t < (rr ? lenB : lenA)) {
          *(f32x4*)&HF[row * 256 + c0e] = hn;
          short4v sv = { f2bf(hn[0]), f2bf(hn[1]), f2bf(hn[2]), f2bf(hn[3]) };
          *(short4v*)(HBF + row * 512 + ((8 * l) ^ ((row & 7) << 4))) = sv;
        }
      }
    }
    __syncthreads();

    // ================= 4 transition layers: 6 jobs/wave each =================
    #pragma unroll 1
    for (int li = 0; li < 4; ++li) {
      const short* btl = bt + (size_t)li * WTT_PER;
      #pragma unroll
      for (int s = 0; s < 6; ++s) {
        f32x4 acc = zero4();
        const short* nxt;
        if (s < 5)       nxt = btl + (size_t)(s + 1) * 4096;
        else if (li < 3) nxt = btl + WTT_PER;     // next layer tile0
        else             nxt = bg;                // next step: gates tile0 half0
        if ((s & 1) == 0) { ld8(B1, nxt); mm8h(B0, acc); }
        else              { ld8(B0, nxt); mm8h(B1, acc); }
        st4(G, (w * 6 + s) * 16, acc);
      }
      __syncthreads();

      // ---- transition elementwise: wave w -> rows 2w, 2w+1 ----
      f32x4 g4r = *(const f32x4*)(tgr + li * 256 + c0e), b4r = *(const f32x4*)(tbr + li * 256 + c0e);
      f32x4 g4z = *(const f32x4*)(tgz + li * 256 + c0e), b4z = *(const f32x4*)(tbz + li * 256 + c0e);
      f32x4 cb4 = *(const f32x4*)(tbc + li * 256 + c0e);
      #pragma unroll
      for (int rr = 0; rr < 2; ++rr) {
        int row = 2 * w + rr;
        f32x4 pr = *(const f32x4*)&G[row * 776 + c0e];
        f32x4 pz = *(const f32x4*)&G[row * 776 + 256 + c0e];
        f32x4 pc = *(const f32x4*)&G[row * 776 + 512 + c0e];
        f32x4 ri = ln_sig(pr, g4r, b4r);
        f32x4 zi = ln_sig(pz, g4z, b4z);
        f32x4 h = *(const f32x4*)&HF[row * 256 + c0e];
        f32x4 hn;
        #pragma unroll
        for (int q = 0; q < 4; ++q) {
          float n = tanhf(ri[q] * (pc[q] + cb4[q]));
          hn[q] = (1.f - zi[q]) * n + zi[q] * h[q];
        }
        bool act = t < (rr ? lenB : lenA);
        if (act) {
          *(f32x4*)&HF[row * 256 + c0e] = hn;
          short4v sv = { f2bf(hn[0]), f2bf(hn[1]), f2bf(hn[2]), f2bf(hn[3]) };
          *(short4v*)(HBF + row * 512 + ((8 * l) ^ ((row & 7) << 4))) = sv;
        }
        if (li == 3) {
          f32x4 o = act ? hn : zero4();
          *(f32x4*)(out + ((size_t)t * B_ + rb0 + row) * H_ + c0e) = o;
        }
      }
      __syncthreads();
    }
  }

  // tail: zero outputs past this WG's longest sequence
  for (int t = maxlen; t < T_; ++t) {
    float* o = out + ((size_t)t * B_ + rb0) * H_;
    for (int i = tid; i < 1024; i += 512)
      ((f32x4*)o)[i] = zero4();
  }
}

extern "C" void kernel_launch(void* const* d_in, const int* in_sizes, int n_in,
                              void* d_out, int out_size, void* d_ws, size_t ws_size,
                              hipStream_t stream) {
  const float* x    = (const float*)d_in[0];
  const int* lengths = (const int*)d_in[1];
  const float* Wr   = (const float*)d_in[2];
  const float* gr   = (const float*)d_in[3];
  const float* br   = (const float*)d_in[4];
  const float* Wz   = (const float*)d_in[5];
  const float* gz   = (const float*)d_in[6];
  const float* bz   = (const float*)d_in[7];
  const float* Wl   = (const float*)d_in[8];
  const float* gl   = (const float*)d_in[9];
  const float* bl   = (const float*)d_in[10];
  const float* Wlt  = (const float*)d_in[11];
  const float* Cx   = (const float*)d_in[12];
  const float* Chw  = (const float*)d_in[13];
  const float* Chb  = (const float*)d_in[14];
  const float* tWr  = (const float*)d_in[15];
  const float* tgr  = (const float*)d_in[16];
  const float* tbr  = (const float*)d_in[17];
  const float* tWz  = (const float*)d_in[18];
  const float* tgz  = (const float*)d_in[19];
  const float* tbz  = (const float*)d_in[20];
  const float* tWc  = (const float*)d_in[21];
  const float* tbc  = (const float*)d_in[22];

  short* wt = (short*)d_ws;

  hipLaunchKernelGGL(prep_weights, dim3((WT_TOTAL + 255) / 256), dim3(256), 0, stream,
                     Wr, Wz, Wl, Wlt, Cx, Chw, tWr, tWz, tWc, wt);
  hipLaunchKernelGGL(rnn8, dim3(8), dim3(512), 0, stream,
                     x, lengths, gr, br, gz, bz, gl, bl, Chb,
                     tgr, tbr, tgz, tbz, tbc, wt, (float*)d_out);
}

// Round 7
// 17768.800 us; speedup vs baseline: 2.3461x; 2.3461x over previous
//
#include <hip/hip_runtime.h>
#include <hip/hip_bf16.h>

#define T_ 512
#define B_ 128
#define D_ 256
#define H_ 256
#define EPS 1e-5f

typedef __attribute__((ext_vector_type(8))) short short8;
typedef __attribute__((ext_vector_type(4))) short short4v;
typedef __attribute__((ext_vector_type(4))) float f32x4;

// ---- weight arena: [16 slices][21 units][8 frags][64 lanes][8 elems] bf16 ----
// slice j = h-cols [16j,16j+16). unit u: 0-5 gates (g=u>>1, half=u&1, K=512),
// 6-8 aux (Cx,Wlt,Chw, K=256), 9-20 trans (li=(u-9)/3, m=(u-9)%3, K=256).
// frag content for lane l (la=l&15,lh=l>>4): W[k = half*256 + lh*8 + kf*32 + e][col j*16+la]
#define SLICE_E  86016
#define WT_TOTAL 1376256

// ws byte offsets past arena
#define STATS_OFFB 2752512UL  // f32 [8cl][2par][96 p][16 wg]   (98304 B)
#define HX_OFFB    2850816UL  // bf16 [8cl][2par][16 row][256]  (131072 B)
#define FLAG_OFFB  2981888UL  // u32 [8cl][2 fam][2 par][16 wg] (2048 B)
#define NFLAGS     512

// LDS layout (bytes)
#define L_XBF  0        // [16][256] bf16 x, XOR-swizzled      (8192)
#define L_HBF  8192     // [16][256] bf16 h, XOR-swizzled      (8192)
#define L_G6   16384    // f32 [6][16][16] preact redistribute (6144)
#define L_SRED 22528    // f32 [96] reduced stats              (512)
#define L_AUX  23040    // 3 units x 8192 (Cx,Wlt,Chw)         (24576)
#define L_TRN  47616    // 12 units x 8192 (transitions)       (98304)
#define L_END  145920

__device__ __forceinline__ short f2bf(float f) {
  unsigned u = __builtin_bit_cast(unsigned, f);
  u = (u + 0x7FFFu + ((u >> 16) & 1u)) >> 16;   // RNE
  return (short)u;
}
__device__ __forceinline__ f32x4 zero4() { f32x4 z = {0.f, 0.f, 0.f, 0.f}; return z; }
__device__ __forceinline__ f32x4 mfma16(short8 a, short8 b, f32x4 c) {
  return __builtin_amdgcn_mfma_f32_16x16x32_bf16(a, b, c, 0, 0, 0);
}
__device__ __forceinline__ void waitv0() { asm volatile("s_waitcnt vmcnt(0)" ::: "memory"); }

// MALL-coherent (agent scope) primitives — correct under ANY WG placement
__device__ __forceinline__ f32x4 ald4(float* p) {
  unsigned long long* q = (unsigned long long*)p;
  unsigned long long a = __hip_atomic_load(q,     __ATOMIC_RELAXED, __HIP_MEMORY_SCOPE_AGENT);
  unsigned long long b = __hip_atomic_load(q + 1, __ATOMIC_RELAXED, __HIP_MEMORY_SCOPE_AGENT);
  f32x4 v;
  v[0] = __builtin_bit_cast(float, (unsigned)(a & 0xffffffffu));
  v[1] = __builtin_bit_cast(float, (unsigned)(a >> 32));
  v[2] = __builtin_bit_cast(float, (unsigned)(b & 0xffffffffu));
  v[3] = __builtin_bit_cast(float, (unsigned)(b >> 32));
  return v;
}
__device__ __forceinline__ void ast1f(float* p, float v) {
  __hip_atomic_store((unsigned*)p, __builtin_bit_cast(unsigned, v),
                     __ATOMIC_RELAXED, __HIP_MEMORY_SCOPE_AGENT);
}

// ---------------- weight prep: f32 -> bf16, frag-major slice layout ----------------
__global__ void prep_weights(const float* __restrict__ Wr, const float* __restrict__ Wz,
                             const float* __restrict__ Wl, const float* __restrict__ Wlt,
                             const float* __restrict__ Cx, const float* __restrict__ Chw,
                             const float* __restrict__ tWr, const float* __restrict__ tWz,
                             const float* __restrict__ tWc, short* __restrict__ wt) {
  int idx = blockIdx.x * 256 + threadIdx.x;
  if (idx >= WT_TOTAL) return;
  int j  = idx / SLICE_E;
  int r  = idx - j * SLICE_E;
  int u  = r >> 12;            // /4096
  int rr = r & 4095;
  int kf = rr >> 9;            // /512
  int le = rr & 511;
  int l  = le >> 3, e = le & 7;
  int la = l & 15, lh = l >> 4;
  int col = j * 16 + la;
  float v;
  if (u < 6) {
    int g = u >> 1, half = u & 1;
    int k = half * 256 + lh * 8 + kf * 32 + e;
    const float* W = (g == 0) ? Wr : (g == 1 ? Wz : Wl);
    v = W[k * 256 + col];
  } else if (u < 9) {
    int a = u - 6;
    int k = lh * 8 + kf * 32 + e;
    const float* W = (a == 0) ? Cx : (a == 1 ? Wlt : Chw);
    v = W[k * 256 + col];
  } else {
    int q = u - 9;
    int li = q / 3, m = q - li * 3;
    int k = lh * 8 + kf * 32 + e;
    const float* W = (m == 0) ? tWr : (m == 1 ? tWz : tWc);
    v = W[(li * 256 + k) * 256 + col];
  }
  wt[idx] = f2bf(v);
}

// ------- stats-exchange kernel: 8 clusters x 16 col-slice WGs, 1 wave each -------
__global__ __launch_bounds__(64)
void rnn_sx(const float* __restrict__ x, const int* __restrict__ lengths,
            const float* __restrict__ gr, const float* __restrict__ br,
            const float* __restrict__ gz, const float* __restrict__ bz,
            const float* __restrict__ gl, const float* __restrict__ bl,
            const float* __restrict__ Chb,
            const float* __restrict__ tgr, const float* __restrict__ tbr,
            const float* __restrict__ tgz, const float* __restrict__ tbz,
            const float* __restrict__ tbc,
            const short* __restrict__ W, float* __restrict__ stats,
            short* __restrict__ hxs, unsigned* __restrict__ flags,
            float* __restrict__ out) {

  __shared__ __align__(16) char smem[L_END];

  const int l  = threadIdx.x;            // single wave
  const int la = l & 15, lh = l >> 4;
  const int amask = (la & 7) << 4;
  const int bid = blockIdx.x;
  const int cl = bid & 7, j = bid >> 3;
  const int rb0 = cl * 16;
  const int myrow = l >> 2, mc = (l & 3) * 4;
  const int cg = j * 16 + mc;            // my 4 global h-cols
  const int colb = (l & 3) * 64;         // staging: my 64-col block of row myrow

  const short* Wsl = W + (size_t)j * SLICE_E;

  // ---- load resident weights (aux + transitions, 120KB) into LDS ----
  #pragma unroll 1
  for (int u = 0; u < 15; ++u) {
    char* dst = smem + ((u < 3) ? (L_AUX + u * 8192) : (L_TRN + (u - 3) * 8192));
    const short* src = Wsl + (size_t)(u + 6) * 4096;
    #pragma unroll
    for (int kf = 0; kf < 8; ++kf)
      *(short8*)(dst + kf * 1024 + l * 16) = *(const short8*)(src + kf * 512 + l * 8);
  }
  for (int i = l; i < 1024; i += 64) ((short4v*)(smem + L_HBF))[i] = (short4v){0, 0, 0, 0};

  int maxlen = 0;
  for (int i = 0; i < 16; ++i) {
    int v = lengths[rb0 + i];
    maxlen = maxlen > v ? maxlen : v;
  }
  const int mylen = lengths[rb0 + myrow];

  float* stc = stats + (size_t)(cl * 2) * 1536;    // + par*1536: [96 p][16 wg] f32
  short* hxc = hxs + (size_t)(cl * 2) * 4096;      // + par*4096: [16][256] bf16
  unsigned* flc = flags + cl * 64;                 // [fam2][par2][16]

  f32x4 hreg = zero4();                            // my (row, 4 cols) f32 h
  int dead = 0;

  auto pollf = [&](unsigned* fb, unsigned tag) {
    if (!dead) {
      int it = 0;
      while (true) {
        unsigned v = tag;
        if (l < 16) v = __hip_atomic_load(fb + l, __ATOMIC_RELAXED, __HIP_MEMORY_SCOPE_AGENT);
        if (__all((int)(v >= tag))) break;
        if (++it > 300000) { dead = 1; break; }
        __builtin_amdgcn_s_sleep(1);
      }
    }
    asm volatile("" ::: "memory");
  };
  auto ldu = [&](short8 (&dst)[8], const short* bp) {     // one 8KB B-unit -> regs
    #pragma unroll
    for (int kf = 0; kf < 8; ++kf) dst[kf] = *(const short8*)(bp + kf * 512 + l * 8);
  };
  auto mm8r = [&](short8 (&Bv)[8], f32x4& acc, int Ab) {  // B regs, A from LDS
    #pragma unroll
    for (int kf = 0; kf < 8; ++kf) {
      int aoff = Ab + la * 512 + (((kf * 64) + lh * 16) ^ amask);
      acc = mfma16(*(const short8*)(smem + aoff), Bv[kf], acc);
    }
  };
  auto mmlds = [&](int Bub, f32x4& acc, int Ab) {         // B and A from LDS
    #pragma unroll
    for (int kf = 0; kf < 8; ++kf) {
      int aoff = Ab + la * 512 + (((kf * 64) + lh * 16) ^ amask);
      short8 bv = *(const short8*)(smem + Bub + kf * 1024 + l * 16);
      acc = mfma16(*(const short8*)(smem + aoff), bv, acc);
    }
  };
  auto g6store = [&](int arr, f32x4 acc) {
    #pragma unroll
    for (int i = 0; i < 4; ++i)
      *(float*)(smem + L_G6 + ((arr * 16 + lh * 4 + i) * 16 + la) * 4) = acc[i];
  };
  auto readhx = [&](int par) {   // full h' [16][256] bf16 -> HBF (swizzled)
    float* hp = (float*)(hxc + par * 4096 + (l >> 2) * 256 + colb);
    int row2 = l >> 2;
    #pragma unroll
    for (int q2 = 0; q2 < 8; ++q2) {
      f32x4 v = ald4(hp + q2 * 4);
      *(f32x4*)(smem + L_HBF + row2 * 512 + ((colb * 2 + q2 * 16) ^ ((row2 & 7) << 4))) = v;
    }
  };
  auto posth = [&](int par) {    // my (row, 4 cols) h -> hx, bf16 packed 8B
    unsigned long long pk =
        (unsigned long long)(unsigned short)f2bf(hreg[0]) |
        ((unsigned long long)(unsigned short)f2bf(hreg[1]) << 16) |
        ((unsigned long long)(unsigned short)f2bf(hreg[2]) << 32) |
        ((unsigned long long)(unsigned short)f2bf(hreg[3]) << 48);
    __hip_atomic_store((unsigned long long*)(hxc + par * 4096 + myrow * 256 + cg), pk,
                       __ATOMIC_RELAXED, __HIP_MEMORY_SCOPE_AGENT);
  };

  short8 B0[8], B1[8];
  ldu(B0, Wsl);                 // gates g0 x-half
  ldu(B1, Wsl + 4096);          // gates g0 h-half

  for (int t = 0; t < maxlen; ++t) {
    // ============================ round G ============================
    int R = t * 5, par = R & 1;
    // stage x_t -> XBF (bf16, swizzled); lane covers (row l>>2, 64 cols)
    {
      const float* xs = x + ((size_t)t * B_ + rb0 + (l >> 2)) * D_ + colb;
      int row2 = l >> 2;
      #pragma unroll
      for (int u2 = 0; u2 < 8; ++u2) {
        f32x4 a = *(const f32x4*)(xs + u2 * 8);
        f32x4 b = *(const f32x4*)(xs + u2 * 8 + 4);
        short8 s;
        s[0] = f2bf(a[0]); s[1] = f2bf(a[1]); s[2] = f2bf(a[2]); s[3] = f2bf(a[3]);
        s[4] = f2bf(b[0]); s[5] = f2bf(b[1]); s[6] = f2bf(b[2]); s[7] = f2bf(b[3]);
        *(short8*)(smem + L_XBF + row2 * 512 + ((colb * 2 + u2 * 16) ^ ((row2 & 7) << 4))) = s;
      }
    }
    // mm: 3 gate cols-tiles (K=512) + 3 aux tiles (K=256), all for my 16 cols
    f32x4 ac[6];
    #pragma unroll
    for (int a2 = 0; a2 < 6; ++a2) ac[a2] = zero4();
    mm8r(B0, ac[0], L_XBF); ldu(B0, Wsl + 2 * 4096);
    mm8r(B1, ac[0], L_HBF); ldu(B1, Wsl + 3 * 4096);
    mm8r(B0, ac[1], L_XBF); ldu(B0, Wsl + 4 * 4096);
    mm8r(B1, ac[1], L_HBF); ldu(B1, Wsl + 5 * 4096);
    mm8r(B0, ac[2], L_XBF);
    mm8r(B1, ac[2], L_HBF);
    mmlds(L_AUX,         ac[3], L_XBF);   // xcx
    mmlds(L_AUX + 8192,  ac[4], L_XBF);   // xwl
    mmlds(L_AUX + 16384, ac[5], L_HBF);   // hch
    #pragma unroll
    for (int a2 = 0; a2 < 6; ++a2) g6store(a2, ac[a2]);
    // my-row preacts
    f32x4 pv[6];
    #pragma unroll
    for (int a2 = 0; a2 < 6; ++a2)
      pv[a2] = *(const f32x4*)(smem + L_G6 + ((a2 * 16 + myrow) * 16 + mc) * 4);
    // partial LN stats over my WG's 16 cols (4-lane row group)
    float st[6];
    #pragma unroll
    for (int g2 = 0; g2 < 3; ++g2) {
      f32x4 v = pv[g2];
      st[2 * g2]     = v[0] + v[1] + v[2] + v[3];
      st[2 * g2 + 1] = v[0] * v[0] + v[1] * v[1] + v[2] * v[2] + v[3] * v[3];
    }
    #pragma unroll
    for (int s2 = 0; s2 < 6; ++s2) {
      st[s2] += __shfl_xor(st[s2], 1);
      st[s2] += __shfl_xor(st[s2], 2);
    }
    float* sp = stc + par * 1536;
    {
      int k4 = l & 3;
      ast1f(sp + (k4 * 16 + myrow) * 16 + j, st[k4]);
      if (k4 < 2) ast1f(sp + ((4 + k4) * 16 + myrow) * 16 + j, st[4 + k4]);
    }
    waitv0();
    if (l == 0)
      __hip_atomic_store(flc + par * 16 + j, (unsigned)(R + 1),
                         __ATOMIC_RELAXED, __HIP_MEMORY_SCOPE_AGENT);
    pollf(flc + par * 16, (unsigned)(R + 1));
    // reduce stats: lane handles p=l (and p=64+l for l<32)
    {
      float* q = sp + l * 16;
      f32x4 a = ald4(q), b = ald4(q + 4), c = ald4(q + 8), d = ald4(q + 12);
      f32x4 s4 = a + b + c + d;
      *(float*)(smem + L_SRED + l * 4) = s4[0] + s4[1] + s4[2] + s4[3];
      if (l < 32) {
        float* q2 = sp + (64 + l) * 16;
        f32x4 a2 = ald4(q2), b2 = ald4(q2 + 4), c2 = ald4(q2 + 8), d2 = ald4(q2 + 12);
        f32x4 t4 = a2 + b2 + c2 + d2;
        *(float*)(smem + L_SRED + (64 + l) * 4) = t4[0] + t4[1] + t4[2] + t4[3];
      }
    }
    // finalize elementwise for my (row, 4 cols)
    {
      float m3[3], rs3[3];
      #pragma unroll
      for (int g2 = 0; g2 < 3; ++g2) {
        float s1 = *(float*)(smem + L_SRED + ((2 * g2) * 16 + myrow) * 4);
        float s2 = *(float*)(smem + L_SRED + ((2 * g2 + 1) * 16 + myrow) * 4);
        float mm = s1 * (1.f / 256.f);
        float vv = s2 * (1.f / 256.f) - mm * mm;
        m3[g2] = mm; rs3[g2] = rsqrtf((vv > 0.f ? vv : 0.f) + EPS);
      }
      f32x4 g4r = *(const f32x4*)(gr + cg), b4r = *(const f32x4*)(br + cg);
      f32x4 g4z = *(const f32x4*)(gz + cg), b4z = *(const f32x4*)(bz + cg);
      f32x4 g4l = *(const f32x4*)(gl + cg), b4l = *(const f32x4*)(bl + cg);
      f32x4 cb4 = *(const f32x4*)(Chb + cg);
      bool act = t < mylen;
      f32x4 hn;
      #pragma unroll
      for (int q2 = 0; q2 < 4; ++q2) {
        float rv = 1.f / (1.f + __expf(-((pv[0][q2] - m3[0]) * rs3[0] * g4r[q2] + b4r[q2])));
        float zv = 1.f / (1.f + __expf(-((pv[1][q2] - m3[1]) * rs3[1] * g4z[q2] + b4z[q2])));
        float lv = 1.f / (1.f + __expf(-((pv[2][q2] - m3[2]) * rs3[2] * g4l[q2] + b4l[q2])));
        float n = tanhf(pv[3][q2] + rv * (pv[5][q2] + cb4[q2])) + lv * pv[4][q2];
        hn[q2] = (1.f - zv) * hreg[q2] + zv * n;
      }
      if (act) hreg = hn;
    }
    posth(par);
    waitv0();
    if (l == 0)
      __hip_atomic_store(flc + (2 + par) * 16 + j, (unsigned)(R + 1),
                         __ATOMIC_RELAXED, __HIP_MEMORY_SCOPE_AGENT);
    pollf(flc + (2 + par) * 16, (unsigned)(R + 1));
    readhx(par);

    // ======================== transition layers ========================
    #pragma unroll 1
    for (int li = 0; li < 4; ++li) {
      R = t * 5 + 1 + li; par = R & 1;
      f32x4 tc0 = zero4(), tc1 = zero4(), tc2 = zero4();
      mmlds(L_TRN + (li * 3 + 0) * 8192, tc0, L_HBF);
      mmlds(L_TRN + (li * 3 + 1) * 8192, tc1, L_HBF);
      mmlds(L_TRN + (li * 3 + 2) * 8192, tc2, L_HBF);
      g6store(0, tc0); g6store(1, tc1); g6store(2, tc2);
      f32x4 qv[3];
      #pragma unroll
      for (int a2 = 0; a2 < 3; ++a2)
        qv[a2] = *(const f32x4*)(smem + L_G6 + ((a2 * 16 + myrow) * 16 + mc) * 4);
      float st4[4];
      #pragma unroll
      for (int g2 = 0; g2 < 2; ++g2) {
        f32x4 v = qv[g2];
        st4[2 * g2]     = v[0] + v[1] + v[2] + v[3];
        st4[2 * g2 + 1] = v[0] * v[0] + v[1] * v[1] + v[2] * v[2] + v[3] * v[3];
      }
      #pragma unroll
      for (int s2 = 0; s2 < 4; ++s2) {
        st4[s2] += __shfl_xor(st4[s2], 1);
        st4[s2] += __shfl_xor(st4[s2], 2);
      }
      float* sp2 = stc + par * 1536;
      ast1f(sp2 + ((l & 3) * 16 + myrow) * 16 + j, st4[l & 3]);
      waitv0();
      if (l == 0)
        __hip_atomic_store(flc + par * 16 + j, (unsigned)(R + 1),
                           __ATOMIC_RELAXED, __HIP_MEMORY_SCOPE_AGENT);
      if (li == 3) {              // prefetch next step's gate g0 units under the polls
        ldu(B0, Wsl);
        ldu(B1, Wsl + 4096);
      }
      pollf(flc + par * 16, (unsigned)(R + 1));
      {
        float* q = sp2 + l * 16;
        f32x4 a = ald4(q), b = ald4(q + 4), c = ald4(q + 8), d = ald4(q + 12);
        f32x4 s4 = a + b + c + d;
        *(float*)(smem + L_SRED + l * 4) = s4[0] + s4[1] + s4[2] + s4[3];
      }
      bool act = t < mylen;
      {
        float m2[2], rs2[2];
        #pragma unroll
        for (int g2 = 0; g2 < 2; ++g2) {
          float s1 = *(float*)(smem + L_SRED + ((2 * g2) * 16 + myrow) * 4);
          float s2 = *(float*)(smem + L_SRED + ((2 * g2 + 1) * 16 + myrow) * 4);
          float mm = s1 * (1.f / 256.f);
          float vv = s2 * (1.f / 256.f) - mm * mm;
          m2[g2] = mm; rs2[g2] = rsqrtf((vv > 0.f ? vv : 0.f) + EPS);
        }
        f32x4 g4r = *(const f32x4*)(tgr + li * 256 + cg), b4r = *(const f32x4*)(tbr + li * 256 + cg);
        f32x4 g4z = *(const f32x4*)(tgz + li * 256 + cg), b4z = *(const f32x4*)(tbz + li * 256 + cg);
        f32x4 cb4 = *(const f32x4*)(tbc + li * 256 + cg);
        f32x4 hn;
        #pragma unroll
        for (int q2 = 0; q2 < 4; ++q2) {
          float rv = 1.f / (1.f + __expf(-((qv[0][q2] - m2[0]) * rs2[0] * g4r[q2] + b4r[q2])));
          float zv = 1.f / (1.f + __expf(-((qv[1][q2] - m2[1]) * rs2[1] * g4z[q2] + b4z[q2])));
          float n = tanhf(rv * (qv[2][q2] + cb4[q2]));
          hn[q2] = (1.f - zv) * n + zv * hreg[q2];
        }
        if (act) hreg = hn;
        if (li == 3) {
          f32x4 o = act ? hreg : zero4();
          *(f32x4*)(out + ((size_t)t * B_ + rb0 + myrow) * H_ + cg) = o;
        }
      }
      posth(par);
      waitv0();
      if (l == 0)
        __hip_atomic_store(flc + (2 + par) * 16 + j, (unsigned)(R + 1),
                           __ATOMIC_RELAXED, __HIP_MEMORY_SCOPE_AGENT);
      pollf(flc + (2 + par) * 16, (unsigned)(R + 1));
      readhx(par);
    }
  }

  // tail: zero my (row, 4 cols) past the cluster's longest sequence
  for (int t2 = maxlen; t2 < T_; ++t2)
    *(f32x4*)(out + ((size_t)t2 * B_ + rb0 + myrow) * H_ + cg) = zero4();
}

extern "C" void kernel_launch(void* const* d_in, const int* in_sizes, int n_in,
                              void* d_out, int out_size, void* d_ws, size_t ws_size,
                              hipStream_t stream) {
  const float* x    = (const float*)d_in[0];
  const int* lengths = (const int*)d_in[1];
  const float* Wr   = (const float*)d_in[2];
  const float* gr   = (const float*)d_in[3];
  const float* br   = (const float*)d_in[4];
  const float* Wz   = (const float*)d_in[5];
  const float* gz   = (const float*)d_in[6];
  const float* bz   = (const float*)d_in[7];
  const float* Wl   = (const float*)d_in[8];
  const float* gl   = (const float*)d_in[9];
  const float* bl   = (const float*)d_in[10];
  const float* Wlt  = (const float*)d_in[11];
  const float* Cx   = (const float*)d_in[12];
  const float* Chw  = (const float*)d_in[13];
  const float* Chb  = (const float*)d_in[14];
  const float* tWr  = (const float*)d_in[15];
  const float* tgr  = (const float*)d_in[16];
  const float* tbr  = (const float*)d_in[17];
  const float* tWz  = (const float*)d_in[18];
  const float* tgz  = (const float*)d_in[19];
  const float* tbz  = (const float*)d_in[20];
  const float* tWc  = (const float*)d_in[21];
  const float* tbc  = (const float*)d_in[22];

  short*    wt    = (short*)d_ws;
  float*    stats = (float*)((char*)d_ws + STATS_OFFB);
  short*    hxs   = (short*)((char*)d_ws + HX_OFFB);
  unsigned* flags = (unsigned*)((char*)d_ws + FLAG_OFFB);

  hipMemsetAsync(flags, 0, NFLAGS * sizeof(unsigned), stream);
  hipLaunchKernelGGL(prep_weights, dim3((WT_TOTAL + 255) / 256), dim3(256), 0, stream,
                     Wr, Wz, Wl, Wlt, Cx, Chw, tWr, tWz, tWc, wt);
  hipLaunchKernelGGL(rnn_sx, dim3(128), dim3(64), 0, stream,
                     x, lengths, gr, br, gz, bz, gl, bl, Chb,
                     tgr, tbr, tgz, tbz, tbc, wt, stats, hxs, flags, (float*)d_out);
}